// Round 10
// baseline (18.954 us; speedup 1.0000x reference)
//
#include <hip/hip_runtime.h>

// GuidedMoEBasic: B=16, D=64, H=768, NE=7, FEAT=776, 2*FEAT=1552
// P = D*(D+1)/2 = 2080 pairs/batch, N = 16*2080 = 33280.
//
// Affine collapse: expert MLP has no nonlinearity ->
//   o[e,n,:] = flat[n]@(W1[e]@W2[e]) + (b1[e]@W2[e]+b2[e]),
//   flat[n] = [conc[b,t], conc[b,end]] -> per-row 12-float pc vectors,
//   cause per pair is O(1) from pc.
// Session model (R1..R9): dur ~= 14.5us fixed replay overhead + sum(bodies);
// in-kernel cross-block sync always >= +18us vs kernel boundaries.
// Minimal-traffic structure (~6.5 MB total = w1 + pooled, each read ONCE):
//   kPre : M=W1@W2 + bias consts (777 blocks, reads w1)
//   kProj: emotion + 12 projections fused off one pooled read per row;
//          tail features 768..775 added after an in-block emotion reduce
//   kPair: O(1) per pair, float4 pc reads (stride 16)

#define H_     768
#define NE_    7
#define FEAT_  776
#define TWOF   1552
#define NROW   1024
#define PAIRS  2080
#define NPAIR  33280
#define EXH    256

// workspace float layout
#define M_OFF   0          // 6208 floats: M[(e*1552 + half*776 + f)*2 + c]
#define BC_OFF  6208       // 4 floats
#define PC_OFF  6212       // 1024*16: pc[row][j], j<12 used

// ---------------------------------------------------------------------------
// K1: blocks 0..775 -> M rows (1 per wave); 776 -> bias consts.
// ---------------------------------------------------------------------------
__global__ __launch_bounds__(256) void kPre(const float* __restrict__ w1,
                                            const float* __restrict__ b1,
                                            const float* __restrict__ w2,
                                            const float* __restrict__ b2,
                                            float* __restrict__ W) {
    const int lane = threadIdx.x & 63;
    const int wave = threadIdx.x >> 6;
    const int blk  = blockIdx.x;

    int e, r = 0;
    float4 a;
    if (blk < 776) {
        const int row = blk * 4 + wave;          // 0..3103
        e = row / TWOF;
        r = row - e * TWOF;
        a = ((const float4*)(w1 + ((size_t)e * TWOF + r) * EXH))[lane];
    } else {
        if (wave >= 2) return;                   // whole-wave uniform exit
        e = wave;
        a = ((const float4*)(b1 + e * EXH))[lane];
    }
    const float4* wv = (const float4*)(w2 + (size_t)e * EXH * 2);
    const float4 q0 = wv[lane * 2];
    const float4 q1 = wv[lane * 2 + 1];
    float a0 = a.x * q0.x + a.y * q0.z + a.z * q1.x + a.w * q1.z;
    float a1 = a.x * q0.y + a.y * q0.w + a.z * q1.y + a.w * q1.w;
#pragma unroll
    for (int off = 32; off; off >>= 1) {
        a0 += __shfl_down(a0, off);
        a1 += __shfl_down(a1, off);
    }
    if (lane == 0) {
        if (blk < 776) {
            W[M_OFF + ((size_t)e * TWOF + r) * 2 + 0] = a0;
            W[M_OFF + ((size_t)e * TWOF + r) * 2 + 1] = a1;
        } else {
            W[BC_OFF + e * 2 + 0] = a0 + b2[e * 2 + 0];
            W[BC_OFF + e * 2 + 1] = a1 + b2[e * 2 + 1];
        }
    }
}

// ---------------------------------------------------------------------------
// K2: one block per row. Thread t owns features 4t..4t+3 (t<192), one float4
// pooled load feeds BOTH the emotion head (7 acc) and the 12 projections.
// After the wave reduce: emotion -> out + LDS, then the f=768..775 tail is
// added to each projection before writing pc.
// ---------------------------------------------------------------------------
__global__ __launch_bounds__(256) void kProj(const float* __restrict__ pooled,
                                             const int* __restrict__ spk,
                                             const float* __restrict__ emo_w,
                                             const float* __restrict__ emo_b,
                                             const float* __restrict__ gate_w,
                                             const float* __restrict__ W,
                                             float* __restrict__ out_emo,
                                             float* __restrict__ pc) {
    __shared__ float redP[4][19];
    __shared__ float eL[8];

    const int row  = blockIdx.x;
    const int t    = threadIdx.x;
    const int lane = t & 63;
    const int wave = t >> 6;

    float pa[19] = {0.f, 0.f, 0.f, 0.f, 0.f, 0.f, 0.f, 0.f, 0.f, 0.f,
                    0.f, 0.f, 0.f, 0.f, 0.f, 0.f, 0.f, 0.f, 0.f};
    if (t < 192) {
        const float4 c4 = *(const float4*)(pooled + (size_t)row * H_ + 4 * t);
        const float* M = W + M_OFF;
#pragma unroll
        for (int half = 0; half < 2; ++half) {
#pragma unroll
            for (int e = 0; e < 2; ++e) {
                const float* mb = M + ((size_t)e * TWOF + half * FEAT_ + 4 * t) * 2;
                const float4 v0 = *(const float4*)mb;
                const float4 v1 = *(const float4*)(mb + 4);
                const int j = half * 4 + e * 2;
                pa[j]     += c4.x * v0.x + c4.y * v0.z + c4.z * v1.x + c4.w * v1.z;
                pa[j + 1] += c4.x * v0.y + c4.y * v0.w + c4.z * v1.y + c4.w * v1.w;
            }
            const float* gb = gate_w + ((size_t)half * FEAT_ + 4 * t) * 2;
            const float4 g0 = *(const float4*)gb;
            const float4 g1 = *(const float4*)(gb + 4);
            pa[8 + half * 2]     += c4.x * g0.x + c4.y * g0.z + c4.z * g1.x + c4.w * g1.z;
            pa[8 + half * 2 + 1] += c4.x * g0.y + c4.y * g0.w + c4.z * g1.y + c4.w * g1.w;
        }
        const float* ew = emo_w + (size_t)(4 * t) * NE_;
#pragma unroll
        for (int k = 0; k < NE_; ++k)
            pa[12 + k] = c4.x * ew[k] + c4.y * ew[NE_ + k] +
                         c4.z * ew[2 * NE_ + k] + c4.w * ew[3 * NE_ + k];
    }
#pragma unroll
    for (int off = 32; off; off >>= 1)
#pragma unroll
        for (int k = 0; k < 19; ++k) pa[k] += __shfl_down(pa[k], off);
    if (lane == 0)
#pragma unroll
        for (int k = 0; k < 19; ++k) redP[wave][k] = pa[k];
    __syncthreads();

    if (t < NE_) {
        const float v = emo_b[t] + redP[0][12 + t] + redP[1][12 + t] +
                        redP[2][12 + t] + redP[3][12 + t];
        out_emo[(size_t)row * NE_ + t] = v;
        eL[t] = v;
    } else if (t == NE_) {
        eL[7] = (float)spk[row];
    }
    __syncthreads();

    if (t < 12) {
        float base = redP[0][t] + redP[1][t] + redP[2][t] + redP[3][t];
        if (t < 8) {                         // M tail: j = half*4 + e*2 + c
            const int half = t >> 2, e = (t >> 1) & 1, c = t & 1;
            const float* mb = W + M_OFF + ((size_t)e * TWOF + half * FEAT_ + H_) * 2 + c;
#pragma unroll
            for (int k = 0; k < 8; ++k) base += eL[k] * mb[2 * k];
        } else {                             // gate tail: j-8 = half*2 + c
            const int half = (t - 8) >> 1, c = (t - 8) & 1;
            const float* gb = gate_w + ((size_t)half * FEAT_ + H_) * 2 + c;
#pragma unroll
            for (int k = 0; k < 8; ++k) base += eL[k] * gb[2 * k];
        }
        pc[(size_t)row * 16 + t] = base;
    }
}

// ---------------------------------------------------------------------------
// K3: one thread per pair; float4 pc reads (stride 16).
// ---------------------------------------------------------------------------
__global__ __launch_bounds__(256) void kPair(const float* __restrict__ pc,
                                             const float* __restrict__ bc,
                                             const float* __restrict__ gate_b,
                                             float* __restrict__ out_cause) {
    const int n = blockIdx.x * 256 + threadIdx.x;
    if (n >= NPAIR) return;
    const int b = n / PAIRS;
    const int p = n - b * PAIRS;

    int end = (int)((sqrtf(8.0f * (float)p + 1.0f) - 1.0f) * 0.5f);
    while ((end + 1) * (end + 2) / 2 <= p) end++;
    while (end * (end + 1) / 2 > p) end--;
    const int tt = p - end * (end + 1) / 2;

    const float* pt = pc + ((size_t)b * 64 + tt) * 16;
    const float* pe = pc + ((size_t)b * 64 + end) * 16;
    const float4 u0 = *(const float4*)pt;          // pt[0..3]
    const float4 u2 = *(const float4*)(pt + 8);    // pt[8..11]
    const float4 v1 = *(const float4*)(pe + 4);    // pe[4..7]
    const float4 v2 = *(const float4*)(pe + 8);    // pe[8..11]

    const float g0 = u2.x + v2.z + gate_b[0];
    const float g1 = u2.y + v2.w + gate_b[1];

    const float o00 = u0.x + v1.x + bc[0];
    const float o01 = u0.y + v1.y + bc[1];
    const float o10 = u0.z + v1.z + bc[2];
    const float o11 = u0.w + v1.w + bc[3];

    out_cause[(size_t)n * 2 + 0] = o00 * g0 + o10 * g1;
    out_cause[(size_t)n * 2 + 1] = o01 * g0 + o11 * g1;
}

// ---------------------------------------------------------------------------
extern "C" void kernel_launch(void* const* d_in, const int* in_sizes, int n_in,
                              void* d_out, int out_size, void* d_ws, size_t ws_size,
                              hipStream_t stream) {
    const float* pooled = (const float*)d_in[0];
    const int*   spk    = (const int*)d_in[1];
    const float* emo_w  = (const float*)d_in[2];
    const float* emo_b  = (const float*)d_in[3];
    const float* gate_w = (const float*)d_in[4];
    const float* gate_b = (const float*)d_in[5];
    const float* exp_w1 = (const float*)d_in[6];
    const float* exp_b1 = (const float*)d_in[7];
    const float* exp_w2 = (const float*)d_in[8];
    const float* exp_b2 = (const float*)d_in[9];

    float* out = (float*)d_out;                 // [1024*7] emotion | [33280*2] cause
    float* W   = (float*)d_ws;

    hipLaunchKernelGGL(kPre, dim3(777), dim3(256), 0, stream,
                       exp_w1, exp_b1, exp_w2, exp_b2, W);
    hipLaunchKernelGGL(kProj, dim3(NROW), dim3(256), 0, stream,
                       pooled, spk, emo_w, emo_b, gate_w, W, out, W + PC_OFF);
    hipLaunchKernelGGL(kPair, dim3((NPAIR + 255) / 256), dim3(256), 0, stream,
                       W + PC_OFF, W + BC_OFF, gate_b, out + NROW * NE_);
}

// Round 11
// 17.079 us; speedup vs baseline: 1.1098x; 1.1098x over previous
//
#include <hip/hip_runtime.h>

// GuidedMoEBasic: B=16, D=64, H=768, NE=7, FEAT=776, 2*FEAT=1552
// P = D*(D+1)/2 = 2080 pairs/batch, N = 16*2080 = 33280.
//
// Affine collapse: expert MLP has no nonlinearity ->
//   o[e,n,:] = flat[n]@(W1[e]@W2[e]) + (b1[e]@W2[e]+b2[e]),
//   flat[n] = [conc[b,t], conc[b,end]] -> per-row 12-float pc vectors,
//   cause per pair is O(1) from pc.
// Session model (R1..R10): dur ~= 14.5us fixed replay overhead + sum(bodies);
// in-kernel cross-block sync always >= +18us vs kernel boundaries; work on
// idle parallel blocks is free, work on the longest kernel's critical path
// is not (R10: fusing emotion into kProj cost +1.5us despite saving 3MB).
// Best measured configuration (17.41us):
//   kPre : M=W1@W2 + bias (blocks 0..776) || emotion rows (777..1032)
//   kProj: 12 projections/row, per-thread c4 from pooled/ws-emo registers
//   kPair: O(1) per pair, float4 pc reads (stride 16)

#define H_     768
#define NE_    7
#define FEAT_  776
#define TWOF   1552
#define NROW   1024
#define PAIRS  2080
#define NPAIR  33280
#define EXH    256

// workspace float layout
#define M_OFF   0          // 6208 floats: M[(e*1552 + half*776 + f)*2 + c]
#define BC_OFF  6208       // 4 floats
#define EMO_OFF 6212       // 1024*8: [row][0..6]=emotion, [7]=spk (float)
#define PC_OFF  14404      // 1024*16: pc[row][j], j<12 used (16B-aligned)

// ---------------------------------------------------------------------------
// K1: blocks 0..775 -> M rows (1 per wave); 776 -> bias consts;
//     777..1032 -> emotion (1 row per wave, 4 rows/block).
// ---------------------------------------------------------------------------
__global__ __launch_bounds__(256) void kPre(const float* __restrict__ w1,
                                            const float* __restrict__ b1,
                                            const float* __restrict__ w2,
                                            const float* __restrict__ b2,
                                            const float* __restrict__ pooled,
                                            const int* __restrict__ spk,
                                            const float* __restrict__ emo_w,
                                            const float* __restrict__ emo_b,
                                            float* __restrict__ W,
                                            float* __restrict__ out_emo) {
    const int lane = threadIdx.x & 63;
    const int wave = threadIdx.x >> 6;
    const int blk  = blockIdx.x;

    if (blk < 777) {
        // ---- M / bias: one 256-deep dot pair per wave ----
        int e, r = 0;
        float4 a;
        if (blk < 776) {
            const int row = blk * 4 + wave;          // 0..3103
            e = row / TWOF;
            r = row - e * TWOF;
            a = ((const float4*)(w1 + ((size_t)e * TWOF + r) * EXH))[lane];
        } else {
            if (wave >= 2) return;                   // whole-wave uniform exit
            e = wave;
            a = ((const float4*)(b1 + e * EXH))[lane];
        }
        const float4* wv = (const float4*)(w2 + (size_t)e * EXH * 2);
        const float4 q0 = wv[lane * 2];
        const float4 q1 = wv[lane * 2 + 1];
        float a0 = a.x * q0.x + a.y * q0.z + a.z * q1.x + a.w * q1.z;
        float a1 = a.x * q0.y + a.y * q0.w + a.z * q1.y + a.w * q1.w;
#pragma unroll
        for (int off = 32; off; off >>= 1) {
            a0 += __shfl_down(a0, off);
            a1 += __shfl_down(a1, off);
        }
        if (lane == 0) {
            if (blk < 776) {
                W[M_OFF + ((size_t)e * TWOF + r) * 2 + 0] = a0;
                W[M_OFF + ((size_t)e * TWOF + r) * 2 + 1] = a1;
            } else {
                W[BC_OFF + e * 2 + 0] = a0 + b2[e * 2 + 0];
                W[BC_OFF + e * 2 + 1] = a1 + b2[e * 2 + 1];
            }
        }
        return;
    }

    // ---- emotion: one row per wave ----
    const int row = (blk - 777) * 4 + wave;          // 0..1023
    const float* pr = pooled + (size_t)row * H_;
    float acc[NE_] = {0.f, 0.f, 0.f, 0.f, 0.f, 0.f, 0.f};
#pragma unroll
    for (int i = 0; i < 12; ++i) {
        const float p = pr[lane + 64 * i];
        const float* ew = emo_w + (size_t)(lane + 64 * i) * NE_;
#pragma unroll
        for (int k = 0; k < NE_; ++k) acc[k] += p * ew[k];
    }
#pragma unroll
    for (int off = 32; off; off >>= 1)
#pragma unroll
        for (int k = 0; k < NE_; ++k) acc[k] += __shfl_down(acc[k], off);
    if (lane == 0) {
        float* er = W + EMO_OFF + (size_t)row * 8;
#pragma unroll
        for (int k = 0; k < NE_; ++k) {
            const float v = acc[k] + emo_b[k];
            out_emo[(size_t)row * NE_ + k] = v;
            er[k] = v;
        }
        er[7] = (float)spk[row];
    }
}

// ---------------------------------------------------------------------------
// K2: one block per row. Thread t owns features 4t..4t+3 (t<194); c4 straight
// from pooled / ws-emo registers -> 12 projections -> shfl + LDS reduce.
// ---------------------------------------------------------------------------
__global__ __launch_bounds__(256) void kProj(const float* __restrict__ pooled,
                                             const float* __restrict__ gate_w,
                                             const float* __restrict__ W,
                                             float* __restrict__ pc) {
    __shared__ float redP[4][12];

    const int row  = blockIdx.x;
    const int t    = threadIdx.x;
    const int lane = t & 63;
    const int wave = t >> 6;

    float4 c4 = {0.f, 0.f, 0.f, 0.f};
    if (t < 192) {
        c4 = *(const float4*)(pooled + (size_t)row * H_ + 4 * t);
    } else if (t < 194) {
        c4 = *(const float4*)(W + EMO_OFF + (size_t)row * 8 + (t - 192) * 4);
    }

    float pa[12] = {0.f, 0.f, 0.f, 0.f, 0.f, 0.f, 0.f, 0.f, 0.f, 0.f, 0.f, 0.f};
    if (t < 194) {
        const float* M = W + M_OFF;
#pragma unroll
        for (int half = 0; half < 2; ++half) {
#pragma unroll
            for (int e = 0; e < 2; ++e) {
                const float* mb = M + ((size_t)e * TWOF + half * FEAT_ + 4 * t) * 2;
                const float4 v0 = *(const float4*)mb;
                const float4 v1 = *(const float4*)(mb + 4);
                const int j = half * 4 + e * 2;
                pa[j]     += c4.x * v0.x + c4.y * v0.z + c4.z * v1.x + c4.w * v1.z;
                pa[j + 1] += c4.x * v0.y + c4.y * v0.w + c4.z * v1.y + c4.w * v1.w;
            }
            const float* gb = gate_w + ((size_t)half * FEAT_ + 4 * t) * 2;
            const float4 g0 = *(const float4*)gb;
            const float4 g1 = *(const float4*)(gb + 4);
            pa[8 + half * 2]     += c4.x * g0.x + c4.y * g0.z + c4.z * g1.x + c4.w * g1.z;
            pa[8 + half * 2 + 1] += c4.x * g0.y + c4.y * g0.w + c4.z * g1.y + c4.w * g1.w;
        }
    }
#pragma unroll
    for (int off = 32; off; off >>= 1)
#pragma unroll
        for (int k = 0; k < 12; ++k) pa[k] += __shfl_down(pa[k], off);
    if (lane == 0)
#pragma unroll
        for (int k = 0; k < 12; ++k) redP[wave][k] = pa[k];
    __syncthreads();

    if (t < 12)
        pc[(size_t)row * 16 + t] = redP[0][t] + redP[1][t] + redP[2][t] + redP[3][t];
}

// ---------------------------------------------------------------------------
// K3: one thread per pair; float4 pc reads (stride 16).
// ---------------------------------------------------------------------------
__global__ __launch_bounds__(256) void kPair(const float* __restrict__ pc,
                                             const float* __restrict__ bc,
                                             const float* __restrict__ gate_b,
                                             float* __restrict__ out_cause) {
    const int n = blockIdx.x * 256 + threadIdx.x;
    if (n >= NPAIR) return;
    const int b = n / PAIRS;
    const int p = n - b * PAIRS;

    int end = (int)((sqrtf(8.0f * (float)p + 1.0f) - 1.0f) * 0.5f);
    while ((end + 1) * (end + 2) / 2 <= p) end++;
    while (end * (end + 1) / 2 > p) end--;
    const int tt = p - end * (end + 1) / 2;

    const float* pt = pc + ((size_t)b * 64 + tt) * 16;
    const float* pe = pc + ((size_t)b * 64 + end) * 16;
    const float4 u0 = *(const float4*)pt;          // pt[0..3]
    const float4 u2 = *(const float4*)(pt + 8);    // pt[8..11]
    const float4 v1 = *(const float4*)(pe + 4);    // pe[4..7]
    const float4 v2 = *(const float4*)(pe + 8);    // pe[8..11]

    const float g0 = u2.x + v2.z + gate_b[0];
    const float g1 = u2.y + v2.w + gate_b[1];

    const float o00 = u0.x + v1.x + bc[0];
    const float o01 = u0.y + v1.y + bc[1];
    const float o10 = u0.z + v1.z + bc[2];
    const float o11 = u0.w + v1.w + bc[3];

    out_cause[(size_t)n * 2 + 0] = o00 * g0 + o10 * g1;
    out_cause[(size_t)n * 2 + 1] = o01 * g0 + o11 * g1;
}

// ---------------------------------------------------------------------------
extern "C" void kernel_launch(void* const* d_in, const int* in_sizes, int n_in,
                              void* d_out, int out_size, void* d_ws, size_t ws_size,
                              hipStream_t stream) {
    const float* pooled = (const float*)d_in[0];
    const int*   spk    = (const int*)d_in[1];
    const float* emo_w  = (const float*)d_in[2];
    const float* emo_b  = (const float*)d_in[3];
    const float* gate_w = (const float*)d_in[4];
    const float* gate_b = (const float*)d_in[5];
    const float* exp_w1 = (const float*)d_in[6];
    const float* exp_b1 = (const float*)d_in[7];
    const float* exp_w2 = (const float*)d_in[8];
    const float* exp_b2 = (const float*)d_in[9];

    float* out = (float*)d_out;                 // [1024*7] emotion | [33280*2] cause
    float* W   = (float*)d_ws;

    hipLaunchKernelGGL(kPre, dim3(1033), dim3(256), 0, stream,
                       exp_w1, exp_b1, exp_w2, exp_b2,
                       pooled, spk, emo_w, emo_b, W, out);
    hipLaunchKernelGGL(kProj, dim3(NROW), dim3(256), 0, stream,
                       pooled, gate_w, W, W + PC_OFF);
    hipLaunchKernelGGL(kPair, dim3((NPAIR + 255) / 256), dim3(256), 0, stream,
                       W + PC_OFF, W + BC_OFF, gate_b, out + NROW * NE_);
}